// Round 1
// 730.743 us; speedup vs baseline: 1.2673x; 1.2673x over previous
//
#include <hip/hip_runtime.h>
#include <math.h>

#define DD 256
#define BB 1024
#define CC 64
#define VV 50000
#define TOPK 10
#define BM 128
#define BN 128
#define BK 64
#define LDK 72          // padded LDS row stride (bf16 elems): 2-way bank alias = free
#define NCHUNK 391      // ceil(VV/BN)
#define MAXCAND 64
#define NT 512          // k_norm_topk block size: 4 blk/CU * 8 waves = 32 waves/CU

typedef __attribute__((ext_vector_type(8))) short bf16x8;
typedef __attribute__((ext_vector_type(4))) short bf16x4;
typedef __attribute__((ext_vector_type(4))) float f32x4;

__device__ inline unsigned short f2bf(float x) {
    unsigned u = __float_as_uint(x);
    unsigned r = (u + 0x7FFFu + ((u >> 16) & 1u)) >> 16;
    return (unsigned short)r;
}

__device__ inline bf16x8 load_bf8(const unsigned short* p) {
    // two 8-byte LDS loads (addresses are 8B-aligned; 16B would not be)
    bf16x4 lo = *(const bf16x4*)p;
    bf16x4 hi = *(const bf16x4*)(p + 4);
    bf16x8 r;
    r[0] = lo[0]; r[1] = lo[1]; r[2] = lo[2]; r[3] = lo[3];
    r[4] = hi[0]; r[5] = hi[1]; r[6] = hi[2]; r[7] = hi[3];
    return r;
}

// ---------------- Kernel 1: gather + attention + phrase (fp32 + bf16 copy) ----------------
__global__ __launch_bounds__(256) void k_phrase(
    const int* __restrict__ wl_ids, const int* __restrict__ wr_ids,
    const int* __restrict__ cl_ids, const int* __restrict__ cr_ids,
    const float* __restrict__ WE, const float* __restrict__ CE,
    const float* __restrict__ W_a, const float* __restrict__ b_a,
    const float* __restrict__ W_c, const float* __restrict__ b_c,
    float* __restrict__ phrase, unsigned short* __restrict__ phraseb)
{
    const int b = blockIdx.x;
    const int t = threadIdx.x;
    __shared__ float s_wl[DD], s_wr[DD], s_align[DD], s_agg0[DD], s_agg1[DD];
    __shared__ float s_part[256];
    __shared__ float s_att[CC];
    __shared__ int s_rid[CC];

    s_wl[t] = WE[(size_t)wl_ids[b] * DD + t];
    s_wr[t] = WE[(size_t)wr_ids[b] * DD + t];
    __syncthreads();

    for (int side = 0; side < 2; ++side) {
        const float* w    = (side == 0) ? s_wl : s_wr;
        const int*   cids = (side == 0) ? (cr_ids + b * CC) : (cl_ids + b * CC);

        float acc = b_a[t];
        #pragma unroll 4
        for (int k = 0; k < DD; ++k) acc = fmaf(w[k], W_a[k * DD + t], acc);
        s_align[t] = tanhf(acc);
        if (t < CC) s_rid[t] = cids[t];
        __syncthreads();

        {
            const int c = t & 63, p = t >> 6;
            const float* crow = CE + (size_t)s_rid[c] * DD + p * 64;
            const float* al = s_align + p * 64;
            float sc = 0.f;
            #pragma unroll 4
            for (int j = 0; j < 64; ++j) sc = fmaf(crow[j], al[j], sc);
            s_part[t] = sc;
        }
        __syncthreads();
        if (t < CC) {
            float s = s_part[t] + s_part[64 + t] + s_part[128 + t] + s_part[192 + t];
            float m = s;
            for (int off = 32; off; off >>= 1) m = fmaxf(m, __shfl_xor(m, off, 64));
            float e = expf(s - m);
            float sum = e;
            for (int off = 32; off; off >>= 1) sum += __shfl_xor(sum, off, 64);
            s_att[t] = e / sum;
        }
        __syncthreads();
        {
            float ag = 0.f;
            #pragma unroll 4
            for (int c = 0; c < CC; ++c)
                ag = fmaf(s_att[c], CE[(size_t)s_rid[c] * DD + t], ag);
            if (side == 0) s_agg0[t] = ag; else s_agg1[t] = ag;
        }
        __syncthreads();
    }

    s_wl[t]  += s_wr[t];
    s_agg0[t] += s_agg1[t];
    __syncthreads();

    float acc = b_c[t];
    #pragma unroll 4
    for (int k = 0; k < DD; ++k) acc = fmaf(s_wl[k],  W_c[k * DD + t], acc);
    #pragma unroll 4
    for (int k = 0; k < DD; ++k) acc = fmaf(s_agg0[k], W_c[(DD + k) * DD + t], acc);
    const float ph = tanhf(acc);
    phrase[b * DD + t] = ph;
    phraseb[b * DD + t] = f2bf(ph);
}

// ---------------- Kernel 2: bf16 MFMA GEMM logits + per-chunk softmax partials ----------------
__global__ __launch_bounds__(256) void k_logits_mfma(
    const unsigned short* __restrict__ phraseb, const float* __restrict__ CE,
    float* __restrict__ out, float* __restrict__ pmax, float* __restrict__ psum)
{
    __shared__ unsigned short sA[BM * LDK];
    __shared__ unsigned short sB[BN * LDK];
    __shared__ float sM[2][BM], sS[2][BM];

    const int t = threadIdx.x;
    const int wave = t >> 6, lane = t & 63;
    const int wm = wave >> 1, wn = wave & 1;
    const int quad = lane >> 4, l15 = lane & 15;
    const int n0 = blockIdx.x * BN, m0 = blockIdx.y * BM;

    f32x4 acc[4][4] = {};

    for (int k0 = 0; k0 < DD; k0 += BK) {
        __syncthreads();
        // stage A: phrase bf16 [128m][64k]
        #pragma unroll
        for (int r = 0; r < 4; ++r) {
            const int idx = t + r * 256;              // [0,1024)
            const int m = idx >> 3, k8 = (idx & 7) * 8;
            const uint4 v = *(const uint4*)(phraseb + (size_t)(m0 + m) * DD + k0 + k8);
            *(uint2*)(sA + m * LDK + k8)     = make_uint2(v.x, v.y);
            *(uint2*)(sA + m * LDK + k8 + 4) = make_uint2(v.z, v.w);
        }
        // stage B: CE fp32 [128n][64k] -> bf16 (cast in flight)
        #pragma unroll
        for (int r = 0; r < 8; ++r) {
            const int idx = t + r * 256;              // [0,2048)
            const int n = idx >> 4, k4 = (idx & 15) * 4;
            const int gn = n0 + n;
            float4 v = make_float4(0.f, 0.f, 0.f, 0.f);
            if (gn < VV) v = *(const float4*)(CE + (size_t)gn * DD + k0 + k4);
            ushort4 h;
            h.x = f2bf(v.x); h.y = f2bf(v.y); h.z = f2bf(v.z); h.w = f2bf(v.w);
            *(ushort4*)(sB + n * LDK + k4) = h;
        }
        __syncthreads();
        #pragma unroll
        for (int kk = 0; kk < BK; kk += 32) {
            bf16x8 af[4], bfr[4];
            #pragma unroll
            for (int i = 0; i < 4; ++i) {
                af[i]  = load_bf8(sA + (wm * 64 + i * 16 + l15) * LDK + kk + quad * 8);
                bfr[i] = load_bf8(sB + (wn * 64 + i * 16 + l15) * LDK + kk + quad * 8);
            }
            #pragma unroll
            for (int i = 0; i < 4; ++i)
                #pragma unroll
                for (int j = 0; j < 4; ++j)
                    acc[i][j] = __builtin_amdgcn_mfma_f32_16x16x32_bf16(af[i], bfr[j], acc[i][j], 0, 0, 0);
        }
    }

    // ---- store logits (fp32) ----
    bool val[4];
    #pragma unroll
    for (int j = 0; j < 4; ++j) val[j] = (n0 + wn * 64 + j * 16 + l15) < VV;

    #pragma unroll
    for (int i = 0; i < 4; ++i) {
        const int mbase = m0 + wm * 64 + i * 16 + quad * 4;
        #pragma unroll
        for (int r = 0; r < 4; ++r) {
            const int gm = mbase + r;
            #pragma unroll
            for (int j = 0; j < 4; ++j) {
                const int gn = n0 + wn * 64 + j * 16 + l15;
                if (val[j]) out[(size_t)gm * VV + gn] = acc[i][j][r];
            }
        }
    }

    // ---- per-row (128-col block) max & sumexp partials (fast exp) ----
    #pragma unroll
    for (int i = 0; i < 4; ++i) {
        #pragma unroll
        for (int r = 0; r < 4; ++r) {
            float mx = -INFINITY;
            #pragma unroll
            for (int j = 0; j < 4; ++j) if (val[j]) mx = fmaxf(mx, acc[i][j][r]);
            #pragma unroll
            for (int off = 8; off >= 1; off >>= 1) mx = fmaxf(mx, __shfl_xor(mx, off, 64));
            float s = 0.f;
            #pragma unroll
            for (int j = 0; j < 4; ++j) if (val[j]) s += __expf(acc[i][j][r] - mx);
            #pragma unroll
            for (int off = 8; off >= 1; off >>= 1) s += __shfl_xor(s, off, 64);
            if (l15 == 0) {
                const int mloc = wm * 64 + i * 16 + quad * 4 + r;
                sM[wn][mloc] = mx;
                sS[wn][mloc] = s;
            }
        }
    }
    __syncthreads();
    if (t < BM) {
        const float Ma = sM[0][t], Mb = sM[1][t];
        const float nM = fmaxf(Ma, Mb);
        const float S = sS[0][t] * __expf(Ma - nM) + sS[1][t] * __expf(Mb - nM);
        pmax[(size_t)(m0 + t) * NCHUNK + blockIdx.x] = nM;
        psum[(size_t)(m0 + t) * NCHUNK + blockIdx.x] = S;
    }
}

// ---------------- Kernel 3: per-row online-softmax stat merge ----------------
__global__ __launch_bounds__(64) void k_rowstats(
    const float* __restrict__ pmax, const float* __restrict__ psum,
    float* __restrict__ rowM, float* __restrict__ rowS)
{
    const int b = blockIdx.x, t = threadIdx.x;
    float M = -INFINITY, S = 0.f;
    for (int c = t; c < NCHUNK; c += 64) {
        const float m = pmax[(size_t)b * NCHUNK + c];
        const float s = psum[(size_t)b * NCHUNK + c];
        const float nM = fmaxf(M, m);
        S = S * __expf(M - nM) + s * __expf(m - nM);
        M = nM;
    }
    #pragma unroll
    for (int off = 32; off; off >>= 1) {
        const float m2 = __shfl_xor(M, off, 64);
        const float s2 = __shfl_xor(S, off, 64);
        const float nM = fmaxf(M, m2);
        S = S * __expf(M - nM) + s2 * __expf(m2 - nM);
        M = nM;
    }
    if (t == 0) { rowM[b] = M; rowS[b] = S; }
}

// ---------------- Kernel 4: normalize in place + cheap p10 estimate + candidate emit ----------------
// Pass 1: y = __expf(x-M)*invS, write back, track per-thread TOP-2 VALUES branchlessly
//         (3 VALU/elem instead of a 10-deep insertion network; we only need a p10
//          *estimate* for the emission threshold — indices come from pass 2, and
//          exactness from k_rescore. Missing a true top-10 value in the estimate can
//          only LOWER the threshold -> candidate superset preserved.)
// Merge:  value-only 10-slot sorted-list tree over 512 threads (20 KB LDS, no indices).
// Pass 2: emit all y >= 0.9 * p10_est (reads hit L2/L3).
__global__ __launch_bounds__(NT) void k_norm_topk(
    float* __restrict__ ylogits, const float* __restrict__ rowM,
    const float* __restrict__ rowS, int* __restrict__ cand_idx,
    int* __restrict__ cand_cnt)
{
    const int b = blockIdx.x, t = threadIdx.x;
    const float M = rowM[b];
    const float invS = 1.f / rowS[b];
    float* row = ylogits + (size_t)b * VV;

    float m1 = -1.f, m2 = -1.f;   // top-2 probabilities (probs > 0, -1 is a safe pad)

    for (int i0 = t * 4; i0 < VV; i0 += NT * 4) {
        const float4 v = *(const float4*)(row + i0);
        float4 y;
        y.x = __expf(v.x - M) * invS;
        y.y = __expf(v.y - M) * invS;
        y.z = __expf(v.z - M) * invS;
        y.w = __expf(v.w - M) * invS;
        *(float4*)(row + i0) = y;
        float lo;
        lo = fminf(y.x, m1); m1 = fmaxf(y.x, m1); m2 = fmaxf(m2, lo);
        lo = fminf(y.y, m1); m1 = fmaxf(y.y, m1); m2 = fmaxf(m2, lo);
        lo = fminf(y.z, m1); m1 = fmaxf(y.z, m1); m2 = fmaxf(m2, lo);
        lo = fminf(y.w, m1); m1 = fmaxf(y.w, m1); m2 = fmaxf(m2, lo);
    }

    __shared__ float sv[NT * TOPK];
    sv[t * TOPK + 0] = m1;
    sv[t * TOPK + 1] = m2;
    #pragma unroll
    for (int j = 2; j < TOPK; ++j) sv[t * TOPK + j] = -1.f;

    for (int span = NT / 2; span >= 1; span >>= 1) {
        __syncthreads();
        if (t < span) {
            const int A = t * TOPK, B2 = (t + span) * TOPK;
            float rv[TOPK];
            int ia = 0, ib = 0;
            #pragma unroll
            for (int j = 0; j < TOPK; ++j) {
                const float av = sv[A + ia], bv = sv[B2 + ib];
                const bool takeA = (av >= bv);
                rv[j] = takeA ? av : bv;
                if (takeA) ++ia; else ++ib;
            }
            #pragma unroll
            for (int j = 0; j < TOPK; ++j) sv[A + j] = rv[j];
        }
    }

    // ---- candidate emission: everything within 10% of the 10th approx prob ----
    __shared__ float s_th;
    __shared__ int s_cnt;
    __shared__ int s_cidx[MAXCAND];
    __syncthreads();
    if (t == 0) { s_th = sv[9] * 0.90f; s_cnt = 0; }
    __syncthreads();
    const float th = s_th;
    for (int i0 = t * 4; i0 < VV; i0 += NT * 4) {
        const float4 y = *(const float4*)(row + i0);
        const float ya[4] = {y.x, y.y, y.z, y.w};
        #pragma unroll
        for (int j = 0; j < 4; ++j) {
            if (ya[j] >= th) {
                const int p = atomicAdd(&s_cnt, 1);
                if (p < MAXCAND) s_cidx[p] = i0 + j;
            }
        }
    }
    __syncthreads();
    if (t == 0) cand_cnt[b] = (s_cnt < MAXCAND) ? s_cnt : MAXCAND;
    if (t < MAXCAND && t < s_cnt) cand_idx[b * MAXCAND + t] = s_cidx[t];
}

// ---------------- Kernel 5: exact fp32 rescore of candidates -> final indices ----------------
__global__ __launch_bounds__(64) void k_rescore(
    const float* __restrict__ phrase, const float* __restrict__ CE,
    const int* __restrict__ cand_idx, const int* __restrict__ cand_cnt,
    float* __restrict__ topk_out)
{
    const int b = blockIdx.x, lane = threadIdx.x;
    int cnt = cand_cnt[b];
    if (cnt > MAXCAND) cnt = MAXCAND;
    __shared__ float s_val[MAXCAND];
    __shared__ int   s_idx[MAXCAND];

    const float4 ph = *(const float4*)(phrase + (size_t)b * DD + lane * 4);
    for (int c = 0; c < cnt; ++c) {
        const int id = cand_idx[b * MAXCAND + c];
        const float4 ce = *(const float4*)(CE + (size_t)id * DD + lane * 4);
        float d = ph.x * ce.x + ph.y * ce.y + ph.z * ce.z + ph.w * ce.w;
        #pragma unroll
        for (int off = 32; off; off >>= 1) d += __shfl_xor(d, off, 64);
        if (lane == 0) { s_val[c] = d; s_idx[c] = id; }
    }
    __syncthreads();
    if (lane == 0) {
        for (int j = 0; j < TOPK; ++j) {
            int best = j;
            for (int c = j + 1; c < cnt; ++c) {
                if (s_val[c] > s_val[best] ||
                    (s_val[c] == s_val[best] && s_idx[c] < s_idx[best])) best = c;
            }
            const float bv = s_val[best]; const int bi = s_idx[best];
            s_val[best] = s_val[j]; s_idx[best] = s_idx[j];
            s_val[j] = bv; s_idx[j] = bi;
            topk_out[b * TOPK + j] = (float)bi;
        }
    }
}

extern "C" void kernel_launch(void* const* d_in, const int* in_sizes, int n_in,
                              void* d_out, int out_size, void* d_ws, size_t ws_size,
                              hipStream_t stream) {
    const int*   wl_ids = (const int*)d_in[0];
    const int*   wr_ids = (const int*)d_in[1];
    const int*   cl_ids = (const int*)d_in[2];
    const int*   cr_ids = (const int*)d_in[3];
    const float* WE     = (const float*)d_in[4];
    const float* CE     = (const float*)d_in[5];
    const float* W_a    = (const float*)d_in[6];
    const float* b_a    = (const float*)d_in[7];
    const float* W_c    = (const float*)d_in[8];
    const float* b_c    = (const float*)d_in[9];

    float* out = (float*)d_out;
    float* ws  = (float*)d_ws;

    float* phrase = ws;                                         // 262144 f
    unsigned short* phraseb = (unsigned short*)(ws + 262144);   // 262144 bf16 = 131072 f
    float* pmax   = ws + 262144 + 131072;                       // 400384 f
    float* psum   = pmax + (size_t)BB * NCHUNK;                 // 400384 f
    float* rowM   = psum + (size_t)BB * NCHUNK;                 // 1024 f
    float* rowS   = rowM + BB;                                  // 1024 f
    int*   cand_idx = (int*)(rowS + BB);                        // 65536 i
    int*   cand_cnt = cand_idx + (size_t)BB * MAXCAND;          // 1024 i
    float* topk_out = out + (size_t)BB * VV;

    k_phrase<<<BB, 256, 0, stream>>>(wl_ids, wr_ids, cl_ids, cr_ids,
                                     WE, CE, W_a, b_a, W_c, b_c, phrase, phraseb);
    dim3 g(NCHUNK, BB / BM);
    k_logits_mfma<<<g, 256, 0, stream>>>(phraseb, CE, out, pmax, psum);
    k_rowstats<<<BB, 64, 0, stream>>>(pmax, psum, rowM, rowS);
    k_norm_topk<<<BB, NT, 0, stream>>>(out, rowM, rowS, cand_idx, cand_cnt);
    k_rescore<<<BB, 64, 0, stream>>>(phrase, CE, cand_idx, cand_cnt, topk_out);
}

// Round 4
// 696.020 us; speedup vs baseline: 1.3305x; 1.0499x over previous
//
#include <hip/hip_runtime.h>
#include <math.h>

#define DD 256
#define BB 1024
#define CC 64
#define VV 50000
#define TOPK 10
#define BM 128
#define BN 128
#define BK 64
#define LDK 72          // padded LDS row stride (bf16): 144 B rows, 16B-aligned; 2-way bank alias = free
#define NCHUNK 391      // ceil(VV/BN)
#define NMBLK 8         // BB/BM
#define NWG (NCHUNK * NMBLK)   // 3128 = 8 * 391 exactly
#define MAXCAND 60      // keeps base workspace (5,038,080 B) below the proven 5,050,368 B footprint

typedef __attribute__((ext_vector_type(8))) short bf16x8;
typedef __attribute__((ext_vector_type(4))) float f32x4;

__device__ inline unsigned short f2bf(float x) {
    unsigned u = __float_as_uint(x);
    unsigned r = (u + 0x7FFFu + ((u >> 16) & 1u)) >> 16;
    return (unsigned short)r;
}

// ---------------- Kernel 0: one-time CE fp32 -> bf16 (halves B fetch, removes per-tile f2bf) ----
__global__ __launch_bounds__(256) void k_prep(
    const float* __restrict__ CE, unsigned short* __restrict__ CEb)
{
    const int i = blockIdx.x * 256 + threadIdx.x;          // 8 elems per thread
    const size_t base = (size_t)i * 8;
    if (base >= (size_t)VV * DD) return;
    const float4 a = *(const float4*)(CE + base);
    const float4 b = *(const float4*)(CE + base + 4);
    uint4 o;
    o.x = (unsigned)f2bf(a.x) | ((unsigned)f2bf(a.y) << 16);
    o.y = (unsigned)f2bf(a.z) | ((unsigned)f2bf(a.w) << 16);
    o.z = (unsigned)f2bf(b.x) | ((unsigned)f2bf(b.y) << 16);
    o.w = (unsigned)f2bf(b.z) | ((unsigned)f2bf(b.w) << 16);
    *(uint4*)(CEb + base) = o;
}

// ---------------- Kernel 1: gather + attention + phrase (fp32 + bf16 copy) ----------------
__global__ __launch_bounds__(256) void k_phrase(
    const int* __restrict__ wl_ids, const int* __restrict__ wr_ids,
    const int* __restrict__ cl_ids, const int* __restrict__ cr_ids,
    const float* __restrict__ WE, const float* __restrict__ CE,
    const float* __restrict__ W_a, const float* __restrict__ b_a,
    const float* __restrict__ W_c, const float* __restrict__ b_c,
    float* __restrict__ phrase, unsigned short* __restrict__ phraseb)
{
    const int b = blockIdx.x;
    const int t = threadIdx.x;
    __shared__ float s_wl[DD], s_wr[DD], s_align[DD], s_agg0[DD], s_agg1[DD];
    __shared__ float s_part[256];
    __shared__ float s_att[CC];
    __shared__ int s_rid[CC];

    s_wl[t] = WE[(size_t)wl_ids[b] * DD + t];
    s_wr[t] = WE[(size_t)wr_ids[b] * DD + t];
    __syncthreads();

    for (int side = 0; side < 2; ++side) {
        const float* w    = (side == 0) ? s_wl : s_wr;
        const int*   cids = (side == 0) ? (cr_ids + b * CC) : (cl_ids + b * CC);

        float acc = b_a[t];
        #pragma unroll 4
        for (int k = 0; k < DD; ++k) acc = fmaf(w[k], W_a[k * DD + t], acc);
        s_align[t] = tanhf(acc);
        if (t < CC) s_rid[t] = cids[t];
        __syncthreads();

        {
            const int c = t & 63, p = t >> 6;
            const float* crow = CE + (size_t)s_rid[c] * DD + p * 64;
            const float* al = s_align + p * 64;
            float sc = 0.f;
            #pragma unroll 4
            for (int j = 0; j < 64; ++j) sc = fmaf(crow[j], al[j], sc);
            s_part[t] = sc;
        }
        __syncthreads();
        if (t < CC) {
            float s = s_part[t] + s_part[64 + t] + s_part[128 + t] + s_part[192 + t];
            float m = s;
            for (int off = 32; off; off >>= 1) m = fmaxf(m, __shfl_xor(m, off, 64));
            float e = expf(s - m);
            float sum = e;
            for (int off = 32; off; off >>= 1) sum += __shfl_xor(sum, off, 64);
            s_att[t] = e / sum;
        }
        __syncthreads();
        {
            float ag = 0.f;
            #pragma unroll 4
            for (int c = 0; c < CC; ++c)
                ag = fmaf(s_att[c], CE[(size_t)s_rid[c] * DD + t], ag);
            if (side == 0) s_agg0[t] = ag; else s_agg1[t] = ag;
        }
        __syncthreads();
    }

    s_wl[t]  += s_wr[t];
    s_agg0[t] += s_agg1[t];
    __syncthreads();

    float acc = b_c[t];
    #pragma unroll 4
    for (int k = 0; k < DD; ++k) acc = fmaf(s_wl[k],  W_c[k * DD + t], acc);
    #pragma unroll 4
    for (int k = 0; k < DD; ++k) acc = fmaf(s_agg0[k], W_c[(DD + k) * DD + t], acc);
    const float ph = tanhf(acc);
    phrase[b * DD + t] = ph;
    phraseb[b * DD + t] = f2bf(ph);
}

// ---------------- Kernel 2: bf16 MFMA GEMM, two passes over the same tiles ----------------
// STATS pass: per-chunk row {max, sumexp} only — NO logit store.
// PROBS pass: recompute accs (same inputs/order -> bit-identical), fuse softmax normalize,
//             store probs once (nontemporal), emit candidates >= rowTh via rare global atomics.
template<bool STATS, bool BF16CE>
__global__ __launch_bounds__(256) void k_gemm(
    const unsigned short* __restrict__ phraseb,
    const float* __restrict__ CE, const unsigned short* __restrict__ CEb,
    float* __restrict__ out,
    float* __restrict__ pmax, float* __restrict__ psum,
    const float* __restrict__ rowM, const float* __restrict__ rowInvS,
    const float* __restrict__ rowTh,
    int* __restrict__ cand_idx, int* __restrict__ cand_cnt)
{
    __shared__ unsigned short sA[BM * LDK];
    __shared__ unsigned short sB[BN * LDK];

    const int t = threadIdx.x;
    const int wave = t >> 6, lane = t & 63;
    const int wm = wave >> 1, wn = wave & 1;
    const int quad = lane >> 4, l15 = lane & 15;

    // XCD-bijective swizzle (3128 = 8*391 exactly): blocks sharing wg%8 (one XCD under
    // round-robin dispatch) cover a contiguous ~49-chunk band -> CE tiles stay L2-resident.
    const int wg = blockIdx.x;
    const int q  = (wg & 7) * NCHUNK + (wg >> 3);
    const int m0 = (q & 7) * BM;
    const int cn = q >> 3;
    const int n0 = cn * BN;

    f32x4 acc[4][4] = {};

    for (int k0 = 0; k0 < DD; k0 += BK) {
        __syncthreads();
        // stage A: phrase bf16 [128m][64k]
        #pragma unroll
        for (int r = 0; r < 4; ++r) {
            const int idx = t + r * 256;              // [0,1024)
            const int m = idx >> 3, k8 = (idx & 7) * 8;
            const uint4 v = *(const uint4*)(phraseb + (size_t)(m0 + m) * DD + k0 + k8);
            *(uint4*)(sA + m * LDK + k8) = v;
        }
        // stage B
        if constexpr (BF16CE) {
            #pragma unroll
            for (int r = 0; r < 4; ++r) {
                const int idx = t + r * 256;          // [0,1024)
                const int n = idx >> 3, k8 = (idx & 7) * 8;
                const int gn = n0 + n;
                uint4 v = make_uint4(0u, 0u, 0u, 0u);
                if (gn < VV) v = *(const uint4*)(CEb + (size_t)gn * DD + k0 + k8);
                *(uint4*)(sB + n * LDK + k8) = v;
            }
        } else {
            #pragma unroll
            for (int r = 0; r < 8; ++r) {
                const int idx = t + r * 256;          // [0,2048)
                const int n = idx >> 4, k4 = (idx & 15) * 4;
                const int gn = n0 + n;
                float4 v = make_float4(0.f, 0.f, 0.f, 0.f);
                if (gn < VV) v = *(const float4*)(CE + (size_t)gn * DD + k0 + k4);
                ushort4 h;
                h.x = f2bf(v.x); h.y = f2bf(v.y); h.z = f2bf(v.z); h.w = f2bf(v.w);
                *(ushort4*)(sB + n * LDK + k4) = h;
            }
        }
        __syncthreads();
        #pragma unroll
        for (int kk = 0; kk < BK; kk += 32) {
            bf16x8 af[4], bfr[4];
            #pragma unroll
            for (int i = 0; i < 4; ++i) {
                af[i]  = *(const bf16x8*)(sA + (wm * 64 + i * 16 + l15) * LDK + kk + quad * 8);
                bfr[i] = *(const bf16x8*)(sB + (wn * 64 + i * 16 + l15) * LDK + kk + quad * 8);
            }
            #pragma unroll
            for (int i = 0; i < 4; ++i)
                #pragma unroll
                for (int j = 0; j < 4; ++j)
                    acc[i][j] = __builtin_amdgcn_mfma_f32_16x16x32_bf16(af[i], bfr[j], acc[i][j], 0, 0, 0);
        }
    }

    bool val[4];
    #pragma unroll
    for (int j = 0; j < 4; ++j) val[j] = (n0 + wn * 64 + j * 16 + l15) < VV;

    if constexpr (STATS) {
        __shared__ float sM[2][BM], sS[2][BM];
        #pragma unroll
        for (int i = 0; i < 4; ++i) {
            #pragma unroll
            for (int r = 0; r < 4; ++r) {
                float m1 = -INFINITY;
                #pragma unroll
                for (int j = 0; j < 4; ++j) if (val[j]) m1 = fmaxf(m1, acc[i][j][r]);
                #pragma unroll
                for (int off = 8; off >= 1; off >>= 1) m1 = fmaxf(m1, __shfl_xor(m1, off, 64));
                float s = 0.f;
                #pragma unroll
                for (int j = 0; j < 4; ++j) if (val[j]) s += __expf(acc[i][j][r] - m1);
                #pragma unroll
                for (int off = 8; off >= 1; off >>= 1) s += __shfl_xor(s, off, 64);
                if (l15 == 0) {
                    const int mloc = wm * 64 + i * 16 + quad * 4 + r;
                    sM[wn][mloc] = m1;
                    sS[wn][mloc] = s;
                }
            }
        }
        __syncthreads();
        if (t < BM) {
            const float Ma = sM[0][t], Mb = sM[1][t];
            const float nM = fmaxf(Ma, Mb);
            const float S  = sS[0][t] * __expf(Ma - nM) + sS[1][t] * __expf(Mb - nM);
            const size_t o = (size_t)(m0 + t) * NCHUNK + cn;
            pmax[o] = nM;
            psum[o] = S;
        }
    } else {
        __shared__ float sMr[BM], sIr[BM], sTr[BM];
        if (t < BM) {
            sMr[t] = rowM[m0 + t];
            sIr[t] = rowInvS[m0 + t];
            sTr[t] = rowTh[m0 + t];
        }
        __syncthreads();
        #pragma unroll
        for (int i = 0; i < 4; ++i) {
            #pragma unroll
            for (int r = 0; r < 4; ++r) {
                const int ml = wm * 64 + i * 16 + quad * 4 + r;
                const int gm = m0 + ml;
                const float M = sMr[ml], inv = sIr[ml], th = sTr[ml];
                #pragma unroll
                for (int j = 0; j < 4; ++j) {
                    if (val[j]) {
                        const int gn = n0 + wn * 64 + j * 16 + l15;
                        const float y = __expf(acc[i][j][r] - M) * inv;
                        __builtin_nontemporal_store(y, out + (size_t)gm * VV + gn);
                        if (y >= th) {
                            const int p = atomicAdd(&cand_cnt[gm], 1);
                            if (p < MAXCAND) cand_idx[gm * MAXCAND + p] = gn;
                        }
                    }
                }
            }
        }
    }
}

// ---------------- Kernel 3: merge per-chunk stats -> rowM, invS, threshold ----------------
// p10 estimate = 10th largest CHUNK MAX. Chunk maxima are row elements, so this is a
// guaranteed UNDERestimate of the true p10 -> threshold lower -> candidate SUPERSET ->
// correct (exact rescore picks the final 10).
__global__ __launch_bounds__(64) void k_rowstats(
    const float* __restrict__ pmax, const float* __restrict__ psum,
    float* __restrict__ rowM, float* __restrict__ rowInvS, float* __restrict__ rowTh,
    int* __restrict__ cand_cnt)
{
    const int b = blockIdx.x, t = threadIdx.x;
    float M = -INFINITY, S = 0.f;
    float top[TOPK];
    #pragma unroll
    for (int j = 0; j < TOPK; ++j) top[j] = -INFINITY;

    for (int c = t; c < NCHUNK; c += 64) {
        const float m = pmax[(size_t)b * NCHUNK + c];
        const float s = psum[(size_t)b * NCHUNK + c];
        const float nM = fmaxf(M, m);
        S = S * __expf(M - nM) + s * __expf(m - nM);
        M = nM;
        if (m > top[TOPK - 1]) {
            float v = m;
            #pragma unroll
            for (int p = 0; p < TOPK; ++p) {
                const float hi = fmaxf(top[p], v), lo = fminf(top[p], v);
                top[p] = hi; v = lo;
            }
        }
    }
    #pragma unroll
    for (int off = 32; off; off >>= 1) {
        const float m2 = __shfl_xor(M, off, 64);
        const float s2 = __shfl_xor(S, off, 64);
        const float nM = fmaxf(M, m2);
        S = S * __expf(M - nM) + s2 * __expf(m2 - nM);
        M = nM;
    }
    // 10 rounds of {global max of per-lane sorted-list heads, pop exactly one instance}
    float v10 = -INFINITY;
    for (int k = 0; k < TOPK; ++k) {
        float g = top[0];
        #pragma unroll
        for (int off = 32; off; off >>= 1) g = fmaxf(g, __shfl_xor(g, off, 64));
        v10 = g;
        const unsigned long long mk = __ballot(top[0] == g);
        if (mk && t == __ffsll(mk) - 1) {
            #pragma unroll
            for (int p = 0; p < TOPK - 1; ++p) top[p] = top[p + 1];
            top[TOPK - 1] = -INFINITY;
        }
    }
    if (t == 0) {
        rowM[b] = M;
        const float inv = 1.f / S;
        rowInvS[b] = inv;
        rowTh[b] = 0.90f * __expf(v10 - M) * inv;
        cand_cnt[b] = 0;
    }
}

// ---------------- Kernel 5: exact fp32 rescore of candidates -> final indices ----------------
__global__ __launch_bounds__(64) void k_rescore(
    const float* __restrict__ phrase, const float* __restrict__ CE,
    const int* __restrict__ cand_idx, const int* __restrict__ cand_cnt,
    float* __restrict__ topk_out)
{
    const int b = blockIdx.x, lane = threadIdx.x;
    int cnt = cand_cnt[b];
    if (cnt > MAXCAND) cnt = MAXCAND;
    __shared__ float s_val[MAXCAND];
    __shared__ int   s_idx[MAXCAND];

    // Hardening: pre-fill so a (theoretically impossible) cnt < TOPK never reads
    // uninitialized LDS in the selection below.
    if (lane < MAXCAND) { s_val[lane] = -INFINITY; s_idx[lane] = 0x7ffffff0; }
    __syncthreads();

    const float4 ph = *(const float4*)(phrase + (size_t)b * DD + lane * 4);
    for (int c = 0; c < cnt; ++c) {
        const int id = cand_idx[b * MAXCAND + c];
        const float4 ce = *(const float4*)(CE + (size_t)id * DD + lane * 4);
        float d = ph.x * ce.x + ph.y * ce.y + ph.z * ce.z + ph.w * ce.w;
        #pragma unroll
        for (int off = 32; off; off >>= 1) d += __shfl_xor(d, off, 64);
        if (lane == 0) { s_val[c] = d; s_idx[c] = id; }
    }
    __syncthreads();
    if (lane == 0) {
        for (int j = 0; j < TOPK; ++j) {
            int best = j;
            for (int c = j + 1; c < cnt; ++c) {
                if (s_val[c] > s_val[best] ||
                    (s_val[c] == s_val[best] && s_idx[c] < s_idx[best])) best = c;
            }
            const float bv = s_val[best]; const int bi = s_idx[best];
            s_val[best] = s_val[j]; s_idx[best] = s_idx[j];
            s_val[j] = bv; s_idx[j] = bi;
            topk_out[b * TOPK + j] = (float)bi;
        }
    }
}

extern "C" void kernel_launch(void* const* d_in, const int* in_sizes, int n_in,
                              void* d_out, int out_size, void* d_ws, size_t ws_size,
                              hipStream_t stream) {
    const int*   wl_ids = (const int*)d_in[0];
    const int*   wr_ids = (const int*)d_in[1];
    const int*   cl_ids = (const int*)d_in[2];
    const int*   cr_ids = (const int*)d_in[3];
    const float* WE     = (const float*)d_in[4];
    const float* CE     = (const float*)d_in[5];
    const float* W_a    = (const float*)d_in[6];
    const float* b_a    = (const float*)d_in[7];
    const float* W_c    = (const float*)d_in[8];
    const float* b_c    = (const float*)d_in[9];

    float* out = (float*)d_out;
    float* ws  = (float*)d_ws;

    // Base layout: 5,038,080 B — strictly within the 5,050,368 B footprint proven by the
    // previous (passing) session's kernel, so ws_size is guaranteed to cover it.
    float* phrase  = ws;                                        // 262144 f
    unsigned short* phraseb = (unsigned short*)(ws + 262144);   // 131072 f
    float* pmax    = ws + 262144 + 131072;                      // 400384 f
    float* psum    = pmax + (size_t)BB * NCHUNK;                // 400384 f
    float* rowM    = psum + (size_t)BB * NCHUNK;                // 1024 f
    float* rowInvS = rowM + BB;                                 // 1024 f
    float* rowTh   = rowInvS + BB;                              // 1024 f
    int*   cand_idx = (int*)(rowTh + BB);                       // BB*60 i
    int*   cand_cnt = cand_idx + (size_t)BB * MAXCAND;          // 1024 i
    float* topk_out = out + (size_t)BB * VV;

    const size_t baseBytes = (size_t)((char*)(cand_cnt + BB) - (char*)ws);
    const size_t ceOff = (baseBytes + 255) & ~(size_t)255;
    const bool bf16ce = ws_size >= ceOff + (size_t)VV * DD * 2;   // +25.6 MB, runtime-gated
    unsigned short* CEb = (unsigned short*)((char*)ws + ceOff);

    k_phrase<<<BB, 256, 0, stream>>>(wl_ids, wr_ids, cl_ids, cr_ids,
                                     WE, CE, W_a, b_a, W_c, b_c, phrase, phraseb);
    if (bf16ce) {
        k_prep<<<(VV * DD / 8 + 255) / 256, 256, 0, stream>>>(CE, CEb);
        k_gemm<true, true><<<NWG, 256, 0, stream>>>(phraseb, CE, CEb, out,
            pmax, psum, rowM, rowInvS, rowTh, cand_idx, cand_cnt);
        k_rowstats<<<BB, 64, 0, stream>>>(pmax, psum, rowM, rowInvS, rowTh, cand_cnt);
        k_gemm<false, true><<<NWG, 256, 0, stream>>>(phraseb, CE, CEb, out,
            pmax, psum, rowM, rowInvS, rowTh, cand_idx, cand_cnt);
    } else {
        k_gemm<true, false><<<NWG, 256, 0, stream>>>(phraseb, CE, CEb, out,
            pmax, psum, rowM, rowInvS, rowTh, cand_idx, cand_cnt);
        k_rowstats<<<BB, 64, 0, stream>>>(pmax, psum, rowM, rowInvS, rowTh, cand_cnt);
        k_gemm<false, false><<<NWG, 256, 0, stream>>>(phraseb, CE, CEb, out,
            pmax, psum, rowM, rowInvS, rowTh, cand_idx, cand_cnt);
    }
    k_rescore<<<BB, 64, 0, stream>>>(phrase, CE, cand_idx, cand_cnt, topk_out);
}

// Round 5
// 654.774 us; speedup vs baseline: 1.4143x; 1.0630x over previous
//
#include <hip/hip_runtime.h>
#include <math.h>

#define DD 256
#define BB 1024
#define CC 64
#define VV 50000
#define TOPK 10
#define BM 128
#define BN 128
#define BK 64
#define LDK 72          // padded LDS row stride (bf16): 144 B rows, 16B-aligned; 2-way bank alias = free
#define NCHUNK 391      // ceil(VV/BN)
#define NMBLK 8         // BB/BM
#define NWG (NCHUNK * NMBLK)   // 3128 = 8 * 391 exactly
#define MAXCAND 60      // keeps base workspace (5,038,080 B) below the proven 5,050,368 B footprint

typedef __attribute__((ext_vector_type(8))) short bf16x8;
typedef __attribute__((ext_vector_type(4))) float f32x4;

__device__ inline unsigned short f2bf(float x) {
    unsigned u = __float_as_uint(x);
    unsigned r = (u + 0x7FFFu + ((u >> 16) & 1u)) >> 16;
    return (unsigned short)r;
}

// ---------------- Kernel 0: one-time CE fp32 -> bf16 (halves B fetch, removes per-tile f2bf) ----
__global__ __launch_bounds__(256) void k_prep(
    const float* __restrict__ CE, unsigned short* __restrict__ CEb)
{
    const int i = blockIdx.x * 256 + threadIdx.x;          // 8 elems per thread
    const size_t base = (size_t)i * 8;
    if (base >= (size_t)VV * DD) return;
    const float4 a = *(const float4*)(CE + base);
    const float4 b = *(const float4*)(CE + base + 4);
    uint4 o;
    o.x = (unsigned)f2bf(a.x) | ((unsigned)f2bf(a.y) << 16);
    o.y = (unsigned)f2bf(a.z) | ((unsigned)f2bf(a.w) << 16);
    o.z = (unsigned)f2bf(b.x) | ((unsigned)f2bf(b.y) << 16);
    o.w = (unsigned)f2bf(b.z) | ((unsigned)f2bf(b.w) << 16);
    *(uint4*)(CEb + base) = o;
}

// ---------------- Kernel 1 (fallback, proven): per-entity gather + attention + phrase ---------
__global__ __launch_bounds__(256) void k_phrase(
    const int* __restrict__ wl_ids, const int* __restrict__ wr_ids,
    const int* __restrict__ cl_ids, const int* __restrict__ cr_ids,
    const float* __restrict__ WE, const float* __restrict__ CE,
    const float* __restrict__ W_a, const float* __restrict__ b_a,
    const float* __restrict__ W_c, const float* __restrict__ b_c,
    float* __restrict__ phrase, unsigned short* __restrict__ phraseb)
{
    const int b = blockIdx.x;
    const int t = threadIdx.x;
    __shared__ float s_wl[DD], s_wr[DD], s_align[DD], s_agg0[DD], s_agg1[DD];
    __shared__ float s_part[256];
    __shared__ float s_att[CC];
    __shared__ int s_rid[CC];

    s_wl[t] = WE[(size_t)wl_ids[b] * DD + t];
    s_wr[t] = WE[(size_t)wr_ids[b] * DD + t];
    __syncthreads();

    for (int side = 0; side < 2; ++side) {
        const float* w    = (side == 0) ? s_wl : s_wr;
        const int*   cids = (side == 0) ? (cr_ids + b * CC) : (cl_ids + b * CC);

        float acc = b_a[t];
        #pragma unroll 4
        for (int k = 0; k < DD; ++k) acc = fmaf(w[k], W_a[k * DD + t], acc);
        s_align[t] = tanhf(acc);
        if (t < CC) s_rid[t] = cids[t];
        __syncthreads();

        {
            const int c = t & 63, p = t >> 6;
            const float* crow = CE + (size_t)s_rid[c] * DD + p * 64;
            const float* al = s_align + p * 64;
            float sc = 0.f;
            #pragma unroll 4
            for (int j = 0; j < 64; ++j) sc = fmaf(crow[j], al[j], sc);
            s_part[t] = sc;
        }
        __syncthreads();
        if (t < CC) {
            float s = s_part[t] + s_part[64 + t] + s_part[128 + t] + s_part[192 + t];
            float m = s;
            for (int off = 32; off; off >>= 1) m = fmaxf(m, __shfl_xor(m, off, 64));
            float e = expf(s - m);
            float sum = e;
            for (int off = 32; off; off >>= 1) sum += __shfl_xor(sum, off, 64);
            s_att[t] = e / sum;
        }
        __syncthreads();
        {
            float ag = 0.f;
            #pragma unroll 4
            for (int c = 0; c < CC; ++c)
                ag = fmaf(s_att[c], CE[(size_t)s_rid[c] * DD + t], ag);
            if (side == 0) s_agg0[t] = ag; else s_agg1[t] = ag;
        }
        __syncthreads();
    }

    s_wl[t]  += s_wr[t];
    s_agg0[t] += s_agg1[t];
    __syncthreads();

    float acc = b_c[t];
    #pragma unroll 4
    for (int k = 0; k < DD; ++k) acc = fmaf(s_wl[k],  W_c[k * DD + t], acc);
    #pragma unroll 4
    for (int k = 0; k < DD; ++k) acc = fmaf(s_agg0[k], W_c[(DD + k) * DD + t], acc);
    const float ph = tanhf(acc);
    phrase[b * DD + t] = ph;
    phraseb[b * DD + t] = f2bf(ph);
}

// ---------------- Kernel 1a: batched align GEMM  [2048,256] @ W_a, fused tanh --------------
// Tile: 32 word-slots (16 entities x {wl,wr}) x 64 cols. Grid = 64 row-tiles x 4 col-groups.
// A-tile in LDS (wave-uniform broadcast reads); W_a streamed coalesced (L2-hot, read ~4x total).
// Also emits wordsum = wl + wr (col-group 0 only).
__global__ __launch_bounds__(256) void k_align(
    const int* __restrict__ wl_ids, const int* __restrict__ wr_ids,
    const float* __restrict__ WE,
    const float* __restrict__ W_a, const float* __restrict__ b_a,
    float* __restrict__ alignbuf, float* __restrict__ wordsum)
{
    __shared__ float sA[32][260];     // 260 pad: float4 reads stay 16B-aligned (1040 = 65*16)
    __shared__ int s_id[32];

    const int t  = threadIdx.x;
    const int rt = blockIdx.x >> 2;   // row-tile [0,64)
    const int cg = blockIdx.x & 3;    // col-group [0,4)
    const int b0 = rt * 16;           // first entity
    const int s0 = rt * 32;           // first slot

    if (t < 32) {
        const int e = b0 + (t >> 1);
        s_id[t] = (t & 1) ? wr_ids[e] : wl_ids[e];
    }
    __syncthreads();

    #pragma unroll 8
    for (int r = 0; r < 32; ++r)
        sA[r][t] = WE[(size_t)s_id[r] * DD + t];
    __syncthreads();

    if (cg == 0) {
        #pragma unroll
        for (int i = 0; i < 16; ++i)
            wordsum[(size_t)(b0 + i) * DD + t] = sA[2 * i][t] + sA[2 * i + 1][t];
    }

    const int c = t & 63, mg = t >> 6;
    const int col = cg * 64 + c;
    const float ba = b_a[col];
    float acc[8];
    #pragma unroll
    for (int j = 0; j < 8; ++j) acc[j] = ba;

    for (int k4 = 0; k4 < 64; ++k4) {
        const int kb = k4 * 4;
        const float w0 = W_a[(size_t)(kb + 0) * DD + col];
        const float w1 = W_a[(size_t)(kb + 1) * DD + col];
        const float w2 = W_a[(size_t)(kb + 2) * DD + col];
        const float w3 = W_a[(size_t)(kb + 3) * DD + col];
        #pragma unroll
        for (int j = 0; j < 8; ++j) {
            const float4 a = *(const float4*)&sA[mg * 8 + j][kb];
            acc[j] = fmaf(a.x, w0, acc[j]);
            acc[j] = fmaf(a.y, w1, acc[j]);
            acc[j] = fmaf(a.z, w2, acc[j]);
            acc[j] = fmaf(a.w, w3, acc[j]);
        }
    }
    #pragma unroll
    for (int j = 0; j < 8; ++j)
        alignbuf[(size_t)(s0 + mg * 8 + j) * DD + col] = tanhf(acc[j]);
}

// ---------------- Kernel 1b: attention (per entity, both sides), CE staged ONCE in LDS ------
// side 0: align(wl) vs cr candidates; side 1: align(wr) vs cl. aggsum = agg_l + agg_r.
__global__ __launch_bounds__(256) void k_attn(
    const int* __restrict__ cl_ids, const int* __restrict__ cr_ids,
    const float* __restrict__ CE, const float* __restrict__ alignbuf,
    float* __restrict__ aggsum)
{
    __shared__ float sC[CC][260];     // 66,560 B; float4 16B-aligned; agg reads 2-way (free)
    __shared__ float sAl[DD];
    __shared__ float s_part[256];
    __shared__ float s_att[CC];
    __shared__ int s_rid[CC];

    const int b = blockIdx.x;
    const int t = threadIdx.x;
    float agg_acc = 0.f;

    for (int side = 0; side < 2; ++side) {
        const int* cids = (side == 0) ? (cr_ids + b * CC) : (cl_ids + b * CC);
        if (t < CC) s_rid[t] = cids[t];
        sAl[t] = alignbuf[(size_t)(2 * b + side) * DD + t];
        __syncthreads();

        #pragma unroll 8
        for (int r = 0; r < CC; ++r)
            sC[r][t] = CE[(size_t)s_rid[r] * DD + t];
        __syncthreads();

        {
            const int c = t & 63, p = t >> 6;
            float sc = 0.f;
            #pragma unroll
            for (int jj = 0; jj < 16; ++jj) {
                const float4 v  = *(const float4*)&sC[c][p * 64 + 4 * jj];
                const float4 al = *(const float4*)&sAl[p * 64 + 4 * jj];
                sc = fmaf(v.x, al.x, sc);
                sc = fmaf(v.y, al.y, sc);
                sc = fmaf(v.z, al.z, sc);
                sc = fmaf(v.w, al.w, sc);
            }
            s_part[t] = sc;
        }
        __syncthreads();
        if (t < CC) {
            float s = s_part[t] + s_part[64 + t] + s_part[128 + t] + s_part[192 + t];
            float m = s;
            for (int off = 32; off; off >>= 1) m = fmaxf(m, __shfl_xor(m, off, 64));
            float e = expf(s - m);
            float sum = e;
            for (int off = 32; off; off >>= 1) sum += __shfl_xor(sum, off, 64);
            s_att[t] = e / sum;
        }
        __syncthreads();
        {
            float ag = 0.f;
            #pragma unroll 8
            for (int c = 0; c < CC; ++c)
                ag = fmaf(s_att[c], sC[c][t], ag);
            agg_acc += ag;
        }
        __syncthreads();   // protect sC/s_att before next side overwrites
    }
    aggsum[(size_t)b * DD + t] = agg_acc;
}

// ---------------- Kernel 1c: phrase GEMM  [1024,512] @ W_c, fused tanh + bf16 copy ----------
// Tile: 16 entities x 64 cols. Grid = 64 x 4. Concat row = [wordsum | aggsum] staged in LDS.
__global__ __launch_bounds__(256) void k_phrase2(
    const float* __restrict__ wordsum, const float* __restrict__ aggsum,
    const float* __restrict__ W_c, const float* __restrict__ b_c,
    float* __restrict__ phrase, unsigned short* __restrict__ phraseb)
{
    __shared__ float sX[16][516];     // 516 pad: float4 16B-aligned (2064 = 129*16)

    const int t  = threadIdx.x;
    const int rt = blockIdx.x >> 2;
    const int cg = blockIdx.x & 3;
    const int b0 = rt * 16;

    #pragma unroll
    for (int i = 0; i < 16; ++i) {
        sX[i][t]       = wordsum[(size_t)(b0 + i) * DD + t];
        sX[i][DD + t]  = aggsum [(size_t)(b0 + i) * DD + t];
    }
    __syncthreads();

    const int c = t & 63, mg = t >> 6;
    const int col = cg * 64 + c;
    const float bc = b_c[col];
    float acc[4];
    #pragma unroll
    for (int j = 0; j < 4; ++j) acc[j] = bc;

    for (int k4 = 0; k4 < 128; ++k4) {
        const int kb = k4 * 4;
        const float w0 = W_c[(size_t)(kb + 0) * DD + col];
        const float w1 = W_c[(size_t)(kb + 1) * DD + col];
        const float w2 = W_c[(size_t)(kb + 2) * DD + col];
        const float w3 = W_c[(size_t)(kb + 3) * DD + col];
        #pragma unroll
        for (int j = 0; j < 4; ++j) {
            const float4 a = *(const float4*)&sX[mg * 4 + j][kb];
            acc[j] = fmaf(a.x, w0, acc[j]);
            acc[j] = fmaf(a.y, w1, acc[j]);
            acc[j] = fmaf(a.z, w2, acc[j]);
            acc[j] = fmaf(a.w, w3, acc[j]);
        }
    }
    #pragma unroll
    for (int j = 0; j < 4; ++j) {
        const int b = b0 + mg * 4 + j;
        const float ph = tanhf(acc[j]);
        phrase[(size_t)b * DD + col] = ph;
        phraseb[(size_t)b * DD + col] = f2bf(ph);
    }
}

// ---------------- Kernel 2: bf16 MFMA GEMM, two passes over the same tiles ----------------
template<bool STATS, bool BF16CE>
__global__ __launch_bounds__(256) void k_gemm(
    const unsigned short* __restrict__ phraseb,
    const float* __restrict__ CE, const unsigned short* __restrict__ CEb,
    float* __restrict__ out,
    float* __restrict__ pmax, float* __restrict__ psum,
    const float* __restrict__ rowM, const float* __restrict__ rowInvS,
    const float* __restrict__ rowTh,
    int* __restrict__ cand_idx, int* __restrict__ cand_cnt)
{
    __shared__ unsigned short sA[BM * LDK];
    __shared__ unsigned short sB[BN * LDK];

    const int t = threadIdx.x;
    const int wave = t >> 6, lane = t & 63;
    const int wm = wave >> 1, wn = wave & 1;
    const int quad = lane >> 4, l15 = lane & 15;

    const int wg = blockIdx.x;
    const int q  = (wg & 7) * NCHUNK + (wg >> 3);
    const int m0 = (q & 7) * BM;
    const int cn = q >> 3;
    const int n0 = cn * BN;

    f32x4 acc[4][4] = {};

    for (int k0 = 0; k0 < DD; k0 += BK) {
        __syncthreads();
        #pragma unroll
        for (int r = 0; r < 4; ++r) {
            const int idx = t + r * 256;
            const int m = idx >> 3, k8 = (idx & 7) * 8;
            const uint4 v = *(const uint4*)(phraseb + (size_t)(m0 + m) * DD + k0 + k8);
            *(uint4*)(sA + m * LDK + k8) = v;
        }
        if constexpr (BF16CE) {
            #pragma unroll
            for (int r = 0; r < 4; ++r) {
                const int idx = t + r * 256;
                const int n = idx >> 3, k8 = (idx & 7) * 8;
                const int gn = n0 + n;
                uint4 v = make_uint4(0u, 0u, 0u, 0u);
                if (gn < VV) v = *(const uint4*)(CEb + (size_t)gn * DD + k0 + k8);
                *(uint4*)(sB + n * LDK + k8) = v;
            }
        } else {
            #pragma unroll
            for (int r = 0; r < 8; ++r) {
                const int idx = t + r * 256;
                const int n = idx >> 4, k4 = (idx & 15) * 4;
                const int gn = n0 + n;
                float4 v = make_float4(0.f, 0.f, 0.f, 0.f);
                if (gn < VV) v = *(const float4*)(CE + (size_t)gn * DD + k0 + k4);
                ushort4 h;
                h.x = f2bf(v.x); h.y = f2bf(v.y); h.z = f2bf(v.z); h.w = f2bf(v.w);
                *(ushort4*)(sB + n * LDK + k4) = h;
            }
        }
        __syncthreads();
        #pragma unroll
        for (int kk = 0; kk < BK; kk += 32) {
            bf16x8 af[4], bfr[4];
            #pragma unroll
            for (int i = 0; i < 4; ++i) {
                af[i]  = *(const bf16x8*)(sA + (wm * 64 + i * 16 + l15) * LDK + kk + quad * 8);
                bfr[i] = *(const bf16x8*)(sB + (wn * 64 + i * 16 + l15) * LDK + kk + quad * 8);
            }
            #pragma unroll
            for (int i = 0; i < 4; ++i)
                #pragma unroll
                for (int j = 0; j < 4; ++j)
                    acc[i][j] = __builtin_amdgcn_mfma_f32_16x16x32_bf16(af[i], bfr[j], acc[i][j], 0, 0, 0);
        }
    }

    bool val[4];
    #pragma unroll
    for (int j = 0; j < 4; ++j) val[j] = (n0 + wn * 64 + j * 16 + l15) < VV;

    if constexpr (STATS) {
        __shared__ float sM[2][BM], sS[2][BM];
        #pragma unroll
        for (int i = 0; i < 4; ++i) {
            #pragma unroll
            for (int r = 0; r < 4; ++r) {
                float m1 = -INFINITY;
                #pragma unroll
                for (int j = 0; j < 4; ++j) if (val[j]) m1 = fmaxf(m1, acc[i][j][r]);
                #pragma unroll
                for (int off = 8; off >= 1; off >>= 1) m1 = fmaxf(m1, __shfl_xor(m1, off, 64));
                float s = 0.f;
                #pragma unroll
                for (int j = 0; j < 4; ++j) if (val[j]) s += __expf(acc[i][j][r] - m1);
                #pragma unroll
                for (int off = 8; off >= 1; off >>= 1) s += __shfl_xor(s, off, 64);
                if (l15 == 0) {
                    const int mloc = wm * 64 + i * 16 + quad * 4 + r;
                    sM[wn][mloc] = m1;
                    sS[wn][mloc] = s;
                }
            }
        }
        __syncthreads();
        if (t < BM) {
            const float Ma = sM[0][t], Mb = sM[1][t];
            const float nM = fmaxf(Ma, Mb);
            const float S  = sS[0][t] * __expf(Ma - nM) + sS[1][t] * __expf(Mb - nM);
            const size_t o = (size_t)(m0 + t) * NCHUNK + cn;
            pmax[o] = nM;
            psum[o] = S;
        }
    } else {
        __shared__ float sMr[BM], sIr[BM], sTr[BM];
        if (t < BM) {
            sMr[t] = rowM[m0 + t];
            sIr[t] = rowInvS[m0 + t];
            sTr[t] = rowTh[m0 + t];
        }
        __syncthreads();
        #pragma unroll
        for (int i = 0; i < 4; ++i) {
            #pragma unroll
            for (int r = 0; r < 4; ++r) {
                const int ml = wm * 64 + i * 16 + quad * 4 + r;
                const int gm = m0 + ml;
                const float M = sMr[ml], inv = sIr[ml], th = sTr[ml];
                #pragma unroll
                for (int j = 0; j < 4; ++j) {
                    if (val[j]) {
                        const int gn = n0 + wn * 64 + j * 16 + l15;
                        const float y = __expf(acc[i][j][r] - M) * inv;
                        __builtin_nontemporal_store(y, out + (size_t)gm * VV + gn);
                        if (y >= th) {
                            const int p = atomicAdd(&cand_cnt[gm], 1);
                            if (p < MAXCAND) cand_idx[gm * MAXCAND + p] = gn;
                        }
                    }
                }
            }
        }
    }
}

// ---------------- Kernel 3: merge per-chunk stats -> rowM, invS, threshold ----------------
__global__ __launch_bounds__(64) void k_rowstats(
    const float* __restrict__ pmax, const float* __restrict__ psum,
    float* __restrict__ rowM, float* __restrict__ rowInvS, float* __restrict__ rowTh,
    int* __restrict__ cand_cnt)
{
    const int b = blockIdx.x, t = threadIdx.x;
    float M = -INFINITY, S = 0.f;
    float top[TOPK];
    #pragma unroll
    for (int j = 0; j < TOPK; ++j) top[j] = -INFINITY;

    for (int c = t; c < NCHUNK; c += 64) {
        const float m = pmax[(size_t)b * NCHUNK + c];
        const float s = psum[(size_t)b * NCHUNK + c];
        const float nM = fmaxf(M, m);
        S = S * __expf(M - nM) + s * __expf(m - nM);
        M = nM;
        if (m > top[TOPK - 1]) {
            float v = m;
            #pragma unroll
            for (int p = 0; p < TOPK; ++p) {
                const float hi = fmaxf(top[p], v), lo = fminf(top[p], v);
                top[p] = hi; v = lo;
            }
        }
    }
    #pragma unroll
    for (int off = 32; off; off >>= 1) {
        const float m2 = __shfl_xor(M, off, 64);
        const float s2 = __shfl_xor(S, off, 64);
        const float nM = fmaxf(M, m2);
        S = S * __expf(M - nM) + s2 * __expf(m2 - nM);
        M = nM;
    }
    float v10 = -INFINITY;
    for (int k = 0; k < TOPK; ++k) {
        float g = top[0];
        #pragma unroll
        for (int off = 32; off; off >>= 1) g = fmaxf(g, __shfl_xor(g, off, 64));
        v10 = g;
        const unsigned long long mk = __ballot(top[0] == g);
        if (mk && t == __ffsll(mk) - 1) {
            #pragma unroll
            for (int p = 0; p < TOPK - 1; ++p) top[p] = top[p + 1];
            top[TOPK - 1] = -INFINITY;
        }
    }
    if (t == 0) {
        rowM[b] = M;
        const float inv = 1.f / S;
        rowInvS[b] = inv;
        rowTh[b] = 0.90f * __expf(v10 - M) * inv;
        cand_cnt[b] = 0;
    }
}

// ---------------- Kernel 5: exact fp32 rescore of candidates -> final indices ----------------
__global__ __launch_bounds__(64) void k_rescore(
    const float* __restrict__ phrase, const float* __restrict__ CE,
    const int* __restrict__ cand_idx, const int* __restrict__ cand_cnt,
    float* __restrict__ topk_out)
{
    const int b = blockIdx.x, lane = threadIdx.x;
    int cnt = cand_cnt[b];
    if (cnt > MAXCAND) cnt = MAXCAND;
    __shared__ float s_val[MAXCAND];
    __shared__ int   s_idx[MAXCAND];

    if (lane < MAXCAND) { s_val[lane] = -INFINITY; s_idx[lane] = 0x7ffffff0; }
    __syncthreads();

    const float4 ph = *(const float4*)(phrase + (size_t)b * DD + lane * 4);
    for (int c = 0; c < cnt; ++c) {
        const int id = cand_idx[b * MAXCAND + c];
        const float4 ce = *(const float4*)(CE + (size_t)id * DD + lane * 4);
        float d = ph.x * ce.x + ph.y * ce.y + ph.z * ce.z + ph.w * ce.w;
        #pragma unroll
        for (int off = 32; off; off >>= 1) d += __shfl_xor(d, off, 64);
        if (lane == 0) { s_val[c] = d; s_idx[c] = id; }
    }
    __syncthreads();
    if (lane == 0) {
        for (int j = 0; j < TOPK; ++j) {
            int best = j;
            for (int c = j + 1; c < cnt; ++c) {
                if (s_val[c] > s_val[best] ||
                    (s_val[c] == s_val[best] && s_idx[c] < s_idx[best])) best = c;
            }
            const float bv = s_val[best]; const int bi = s_idx[best];
            s_val[best] = s_val[j]; s_idx[best] = s_idx[j];
            s_val[j] = bv; s_idx[j] = bi;
            topk_out[b * TOPK + j] = (float)bi;
        }
    }
}

extern "C" void kernel_launch(void* const* d_in, const int* in_sizes, int n_in,
                              void* d_out, int out_size, void* d_ws, size_t ws_size,
                              hipStream_t stream) {
    const int*   wl_ids = (const int*)d_in[0];
    const int*   wr_ids = (const int*)d_in[1];
    const int*   cl_ids = (const int*)d_in[2];
    const int*   cr_ids = (const int*)d_in[3];
    const float* WE     = (const float*)d_in[4];
    const float* CE     = (const float*)d_in[5];
    const float* W_a    = (const float*)d_in[6];
    const float* b_a    = (const float*)d_in[7];
    const float* W_c    = (const float*)d_in[8];
    const float* b_c    = (const float*)d_in[9];

    float* out = (float*)d_out;
    float* ws  = (float*)d_ws;

    // Base layout: 5,038,080 B — within the 5,050,368 B footprint proven by prior sessions.
    float* phrase  = ws;                                        // 262144 f
    unsigned short* phraseb = (unsigned short*)(ws + 262144);   // 131072 f
    float* pmax    = ws + 262144 + 131072;                      // 400384 f
    float* psum    = pmax + (size_t)BB * NCHUNK;                // 400384 f
    float* rowM    = psum + (size_t)BB * NCHUNK;                // 1024 f
    float* rowInvS = rowM + BB;                                 // 1024 f
    float* rowTh   = rowInvS + BB;                              // 1024 f
    int*   cand_idx = (int*)(rowTh + BB);                       // BB*60 i
    int*   cand_cnt = cand_idx + (size_t)BB * MAXCAND;          // 1024 i
    float* topk_out = out + (size_t)BB * VV;

    const size_t baseBytes = (size_t)((char*)(cand_cnt + BB) - (char*)ws);

    // ext1 (new phrase pipeline): alignbuf 2 MB + wordsum 1 MB + aggsum 1 MB
    float* alignbuf = (float*)((char*)ws + baseBytes);          // 2048*256 f
    float* wordsum  = alignbuf + (size_t)2 * BB * DD;           // 1024*256 f
    float* aggsum   = wordsum + (size_t)BB * DD;                // 1024*256 f
    const size_t ext1End = baseBytes + (size_t)4 * BB * DD * 4; // +4,194,304 B
    const bool newphrase = ws_size >= ext1End;

    const size_t ceOff = ((newphrase ? ext1End : baseBytes) + 255) & ~(size_t)255;
    const bool bf16ce = ws_size >= ceOff + (size_t)VV * DD * 2;  // +25.6 MB, runtime-gated
    unsigned short* CEb = (unsigned short*)((char*)ws + ceOff);

    if (newphrase) {
        k_align<<<256, 256, 0, stream>>>(wl_ids, wr_ids, WE, W_a, b_a, alignbuf, wordsum);
        k_attn<<<BB, 256, 0, stream>>>(cl_ids, cr_ids, CE, alignbuf, aggsum);
        k_phrase2<<<256, 256, 0, stream>>>(wordsum, aggsum, W_c, b_c, phrase, phraseb);
    } else {
        k_phrase<<<BB, 256, 0, stream>>>(wl_ids, wr_ids, cl_ids, cr_ids,
                                         WE, CE, W_a, b_a, W_c, b_c, phrase, phraseb);
    }
    if (bf16ce) {
        k_prep<<<(VV * DD / 8 + 255) / 256, 256, 0, stream>>>(CE, CEb);
        k_gemm<true, true><<<NWG, 256, 0, stream>>>(phraseb, CE, CEb, out,
            pmax, psum, rowM, rowInvS, rowTh, cand_idx, cand_cnt);
        k_rowstats<<<BB, 64, 0, stream>>>(pmax, psum, rowM, rowInvS, rowTh, cand_cnt);
        k_gemm<false, true><<<NWG, 256, 0, stream>>>(phraseb, CE, CEb, out,
            pmax, psum, rowM, rowInvS, rowTh, cand_idx, cand_cnt);
    } else {
        k_gemm<true, false><<<NWG, 256, 0, stream>>>(phraseb, CE, CEb, out,
            pmax, psum, rowM, rowInvS, rowTh, cand_idx, cand_cnt);
        k_rowstats<<<BB, 64, 0, stream>>>(pmax, psum, rowM, rowInvS, rowTh, cand_cnt);
        k_gemm<false, false><<<NWG, 256, 0, stream>>>(phraseb, CE, CEb, out,
            pmax, psum, rowM, rowInvS, rowTh, cand_idx, cand_cnt);
    }
    k_rescore<<<BB, 64, 0, stream>>>(phrase, CE, cand_idx, cand_cnt, topk_out);
}

// Round 7
// 642.245 us; speedup vs baseline: 1.4419x; 1.0195x over previous
//
#include <hip/hip_runtime.h>
#include <math.h>

#define DD 256
#define BB 1024
#define CC 64
#define VV 50000
#define TOPK 10
#define BM 128
#define BN 128
#define BK 64
#define LDK 72          // padded LDS row stride (bf16): 144 B rows, 16B-aligned; 2-way bank alias = free
#define NCHUNK 391      // ceil(VV/BN)
#define NMBLK 8         // BB/BM
#define NWG (NCHUNK * NMBLK)   // 3128 = 8 * 391 exactly
#define MAXCAND 60      // keeps base workspace (5,038,080 B) below the proven 5,050,368 B footprint

typedef __attribute__((ext_vector_type(8))) short bf16x8;
typedef __attribute__((ext_vector_type(4))) float f32x4;

__device__ inline unsigned short f2bf(float x) {
    unsigned u = __float_as_uint(x);
    unsigned r = (u + 0x7FFFu + ((u >> 16) & 1u)) >> 16;
    return (unsigned short)r;
}

// ---------------- Kernel 0: one-time CE fp32 -> bf16 (halves B fetch, removes per-tile f2bf) ----
__global__ __launch_bounds__(256) void k_prep(
    const float* __restrict__ CE, unsigned short* __restrict__ CEb)
{
    const int i = blockIdx.x * 256 + threadIdx.x;          // 8 elems per thread
    const size_t base = (size_t)i * 8;
    if (base >= (size_t)VV * DD) return;
    const float4 a = *(const float4*)(CE + base);
    const float4 b = *(const float4*)(CE + base + 4);
    uint4 o;
    o.x = (unsigned)f2bf(a.x) | ((unsigned)f2bf(a.y) << 16);
    o.y = (unsigned)f2bf(a.z) | ((unsigned)f2bf(a.w) << 16);
    o.z = (unsigned)f2bf(b.x) | ((unsigned)f2bf(b.y) << 16);
    o.w = (unsigned)f2bf(b.z) | ((unsigned)f2bf(b.w) << 16);
    *(uint4*)(CEb + base) = o;
}

// ---------------- Kernel 1 (fallback, proven): per-entity gather + attention + phrase ---------
__global__ __launch_bounds__(256) void k_phrase(
    const int* __restrict__ wl_ids, const int* __restrict__ wr_ids,
    const int* __restrict__ cl_ids, const int* __restrict__ cr_ids,
    const float* __restrict__ WE, const float* __restrict__ CE,
    const float* __restrict__ W_a, const float* __restrict__ b_a,
    const float* __restrict__ W_c, const float* __restrict__ b_c,
    float* __restrict__ phrase, unsigned short* __restrict__ phraseb)
{
    const int b = blockIdx.x;
    const int t = threadIdx.x;
    __shared__ float s_wl[DD], s_wr[DD], s_align[DD], s_agg0[DD], s_agg1[DD];
    __shared__ float s_part[256];
    __shared__ float s_att[CC];
    __shared__ int s_rid[CC];

    s_wl[t] = WE[(size_t)wl_ids[b] * DD + t];
    s_wr[t] = WE[(size_t)wr_ids[b] * DD + t];
    __syncthreads();

    for (int side = 0; side < 2; ++side) {
        const float* w    = (side == 0) ? s_wl : s_wr;
        const int*   cids = (side == 0) ? (cr_ids + b * CC) : (cl_ids + b * CC);

        float acc = b_a[t];
        #pragma unroll 4
        for (int k = 0; k < DD; ++k) acc = fmaf(w[k], W_a[k * DD + t], acc);
        s_align[t] = tanhf(acc);
        if (t < CC) s_rid[t] = cids[t];
        __syncthreads();

        {
            const int c = t & 63, p = t >> 6;
            const float* crow = CE + (size_t)s_rid[c] * DD + p * 64;
            const float* al = s_align + p * 64;
            float sc = 0.f;
            #pragma unroll 4
            for (int j = 0; j < 64; ++j) sc = fmaf(crow[j], al[j], sc);
            s_part[t] = sc;
        }
        __syncthreads();
        if (t < CC) {
            float s = s_part[t] + s_part[64 + t] + s_part[128 + t] + s_part[192 + t];
            float m = s;
            for (int off = 32; off; off >>= 1) m = fmaxf(m, __shfl_xor(m, off, 64));
            float e = expf(s - m);
            float sum = e;
            for (int off = 32; off; off >>= 1) sum += __shfl_xor(sum, off, 64);
            s_att[t] = e / sum;
        }
        __syncthreads();
        {
            float ag = 0.f;
            #pragma unroll 4
            for (int c = 0; c < CC; ++c)
                ag = fmaf(s_att[c], CE[(size_t)s_rid[c] * DD + t], ag);
            if (side == 0) s_agg0[t] = ag; else s_agg1[t] = ag;
        }
        __syncthreads();
    }

    s_wl[t]  += s_wr[t];
    s_agg0[t] += s_agg1[t];
    __syncthreads();

    float acc = b_c[t];
    #pragma unroll 4
    for (int k = 0; k < DD; ++k) acc = fmaf(s_wl[k],  W_c[k * DD + t], acc);
    #pragma unroll 4
    for (int k = 0; k < DD; ++k) acc = fmaf(s_agg0[k], W_c[(DD + k) * DD + t], acc);
    const float ph = tanhf(acc);
    phrase[b * DD + t] = ph;
    phraseb[b * DD + t] = f2bf(ph);
}

// ---------------- Kernel 1a: batched align GEMM  [2048,256] @ W_a, fused tanh --------------
__global__ __launch_bounds__(256) void k_align(
    const int* __restrict__ wl_ids, const int* __restrict__ wr_ids,
    const float* __restrict__ WE,
    const float* __restrict__ W_a, const float* __restrict__ b_a,
    float* __restrict__ alignbuf, float* __restrict__ wordsum)
{
    __shared__ float sA[32][260];     // 260 pad: float4 reads stay 16B-aligned (1040 = 65*16)
    __shared__ int s_id[32];

    const int t  = threadIdx.x;
    const int rt = blockIdx.x >> 2;   // row-tile [0,64)
    const int cg = blockIdx.x & 3;    // col-group [0,4)
    const int b0 = rt * 16;           // first entity
    const int s0 = rt * 32;           // first slot

    if (t < 32) {
        const int e = b0 + (t >> 1);
        s_id[t] = (t & 1) ? wr_ids[e] : wl_ids[e];
    }
    __syncthreads();

    #pragma unroll 8
    for (int r = 0; r < 32; ++r)
        sA[r][t] = WE[(size_t)s_id[r] * DD + t];
    __syncthreads();

    if (cg == 0) {
        #pragma unroll
        for (int i = 0; i < 16; ++i)
            wordsum[(size_t)(b0 + i) * DD + t] = sA[2 * i][t] + sA[2 * i + 1][t];
    }

    const int c = t & 63, mg = t >> 6;
    const int col = cg * 64 + c;
    const float ba = b_a[col];
    float acc[8];
    #pragma unroll
    for (int j = 0; j < 8; ++j) acc[j] = ba;

    for (int k4 = 0; k4 < 64; ++k4) {
        const int kb = k4 * 4;
        const float w0 = W_a[(size_t)(kb + 0) * DD + col];
        const float w1 = W_a[(size_t)(kb + 1) * DD + col];
        const float w2 = W_a[(size_t)(kb + 2) * DD + col];
        const float w3 = W_a[(size_t)(kb + 3) * DD + col];
        #pragma unroll
        for (int j = 0; j < 8; ++j) {
            const float4 a = *(const float4*)&sA[mg * 8 + j][kb];
            acc[j] = fmaf(a.x, w0, acc[j]);
            acc[j] = fmaf(a.y, w1, acc[j]);
            acc[j] = fmaf(a.z, w2, acc[j]);
            acc[j] = fmaf(a.w, w3, acc[j]);
        }
    }
    #pragma unroll
    for (int j = 0; j < 8; ++j)
        alignbuf[(size_t)(s0 + mg * 8 + j) * DD + col] = tanhf(acc[j]);
}

// ---------------- Kernel 1b: attention (per entity, both sides), CE staged ONCE in LDS ------
__global__ __launch_bounds__(256) void k_attn(
    const int* __restrict__ cl_ids, const int* __restrict__ cr_ids,
    const float* __restrict__ CE, const float* __restrict__ alignbuf,
    float* __restrict__ aggsum)
{
    __shared__ float sC[CC][260];     // 66,560 B; float4 16B-aligned; agg reads 2-way (free)
    __shared__ float sAl[DD];
    __shared__ float s_part[256];
    __shared__ float s_att[CC];
    __shared__ int s_rid[CC];

    const int b = blockIdx.x;
    const int t = threadIdx.x;
    float agg_acc = 0.f;

    for (int side = 0; side < 2; ++side) {
        const int* cids = (side == 0) ? (cr_ids + b * CC) : (cl_ids + b * CC);
        if (t < CC) s_rid[t] = cids[t];
        sAl[t] = alignbuf[(size_t)(2 * b + side) * DD + t];
        __syncthreads();

        #pragma unroll 8
        for (int r = 0; r < CC; ++r)
            sC[r][t] = CE[(size_t)s_rid[r] * DD + t];
        __syncthreads();

        {
            const int c = t & 63, p = t >> 6;
            float sc = 0.f;
            #pragma unroll
            for (int jj = 0; jj < 16; ++jj) {
                const float4 v  = *(const float4*)&sC[c][p * 64 + 4 * jj];
                const float4 al = *(const float4*)&sAl[p * 64 + 4 * jj];
                sc = fmaf(v.x, al.x, sc);
                sc = fmaf(v.y, al.y, sc);
                sc = fmaf(v.z, al.z, sc);
                sc = fmaf(v.w, al.w, sc);
            }
            s_part[t] = sc;
        }
        __syncthreads();
        if (t < CC) {
            float s = s_part[t] + s_part[64 + t] + s_part[128 + t] + s_part[192 + t];
            float m = s;
            for (int off = 32; off; off >>= 1) m = fmaxf(m, __shfl_xor(m, off, 64));
            float e = expf(s - m);
            float sum = e;
            for (int off = 32; off; off >>= 1) sum += __shfl_xor(sum, off, 64);
            s_att[t] = e / sum;
        }
        __syncthreads();
        {
            float ag = 0.f;
            #pragma unroll 8
            for (int c = 0; c < CC; ++c)
                ag = fmaf(s_att[c], sC[c][t], ag);
            agg_acc += ag;
        }
        __syncthreads();   // protect sC/s_att before next side overwrites
    }
    aggsum[(size_t)b * DD + t] = agg_acc;
}

// ---------------- Kernel 1c: phrase GEMM  [1024,512] @ W_c, fused tanh + bf16 copy ----------
__global__ __launch_bounds__(256) void k_phrase2(
    const float* __restrict__ wordsum, const float* __restrict__ aggsum,
    const float* __restrict__ W_c, const float* __restrict__ b_c,
    float* __restrict__ phrase, unsigned short* __restrict__ phraseb)
{
    __shared__ float sX[16][516];     // 516 pad: float4 16B-aligned (2064 = 129*16)

    const int t  = threadIdx.x;
    const int rt = blockIdx.x >> 2;
    const int cg = blockIdx.x & 3;
    const int b0 = rt * 16;

    #pragma unroll
    for (int i = 0; i < 16; ++i) {
        sX[i][t]       = wordsum[(size_t)(b0 + i) * DD + t];
        sX[i][DD + t]  = aggsum [(size_t)(b0 + i) * DD + t];
    }
    __syncthreads();

    const int c = t & 63, mg = t >> 6;
    const int col = cg * 64 + c;
    const float bc = b_c[col];
    float acc[4];
    #pragma unroll
    for (int j = 0; j < 4; ++j) acc[j] = bc;

    for (int k4 = 0; k4 < 128; ++k4) {
        const int kb = k4 * 4;
        const float w0 = W_c[(size_t)(kb + 0) * DD + col];
        const float w1 = W_c[(size_t)(kb + 1) * DD + col];
        const float w2 = W_c[(size_t)(kb + 2) * DD + col];
        const float w3 = W_c[(size_t)(kb + 3) * DD + col];
        #pragma unroll
        for (int j = 0; j < 4; ++j) {
            const float4 a = *(const float4*)&sX[mg * 4 + j][kb];
            acc[j] = fmaf(a.x, w0, acc[j]);
            acc[j] = fmaf(a.y, w1, acc[j]);
            acc[j] = fmaf(a.z, w2, acc[j]);
            acc[j] = fmaf(a.w, w3, acc[j]);
        }
    }
    #pragma unroll
    for (int j = 0; j < 4; ++j) {
        const int b = b0 + mg * 4 + j;
        const float ph = tanhf(acc[j]);
        phrase[(size_t)b * DD + col] = ph;
        phraseb[(size_t)b * DD + col] = f2bf(ph);
    }
}

// ---------------- Kernel 2: bf16 MFMA GEMM, two passes over the same tiles ----------------
// STATS: per-chunk row {max, sumexp}. PROBS: recompute accs, normalize, COALESCED prob store
// via LDS-staged transpose (sA/sB reused as f32 staging after the K-loop — barrier-protected).
template<bool STATS, bool BF16CE>
__global__ __launch_bounds__(256) void k_gemm(
    const unsigned short* __restrict__ phraseb,
    const float* __restrict__ CE, const unsigned short* __restrict__ CEb,
    float* __restrict__ out,
    float* __restrict__ pmax, float* __restrict__ psum,
    const float* __restrict__ rowM, const float* __restrict__ rowInvS,
    const float* __restrict__ rowTh,
    int* __restrict__ cand_idx, int* __restrict__ cand_cnt)
{
    __shared__ __align__(16) char smem_raw[BM * LDK * 2 * 2];   // sA | sB (36,864 B)
    unsigned short* sA = (unsigned short*)smem_raw;
    unsigned short* sB = sA + BM * LDK;

    const int t = threadIdx.x;
    const int wave = t >> 6, lane = t & 63;
    const int wm = wave >> 1, wn = wave & 1;
    const int quad = lane >> 4, l15 = lane & 15;

    const int wg = blockIdx.x;
    const int q  = (wg & 7) * NCHUNK + (wg >> 3);
    const int m0 = (q & 7) * BM;
    const int cn = q >> 3;
    const int n0 = cn * BN;

    f32x4 acc[4][4] = {};

    for (int k0 = 0; k0 < DD; k0 += BK) {
        __syncthreads();
        #pragma unroll
        for (int r = 0; r < 4; ++r) {
            const int idx = t + r * 256;
            const int m = idx >> 3, k8 = (idx & 7) * 8;
            const uint4 v = *(const uint4*)(phraseb + (size_t)(m0 + m) * DD + k0 + k8);
            *(uint4*)(sA + m * LDK + k8) = v;
        }
        if constexpr (BF16CE) {
            #pragma unroll
            for (int r = 0; r < 4; ++r) {
                const int idx = t + r * 256;
                const int n = idx >> 3, k8 = (idx & 7) * 8;
                const int gn = n0 + n;
                uint4 v = make_uint4(0u, 0u, 0u, 0u);
                if (gn < VV) v = *(const uint4*)(CEb + (size_t)gn * DD + k0 + k8);
                *(uint4*)(sB + n * LDK + k8) = v;
            }
        } else {
            #pragma unroll
            for (int r = 0; r < 8; ++r) {
                const int idx = t + r * 256;
                const int n = idx >> 4, k4 = (idx & 15) * 4;
                const int gn = n0 + n;
                float4 v = make_float4(0.f, 0.f, 0.f, 0.f);
                if (gn < VV) v = *(const float4*)(CE + (size_t)gn * DD + k0 + k4);
                ushort4 h;
                h.x = f2bf(v.x); h.y = f2bf(v.y); h.z = f2bf(v.z); h.w = f2bf(v.w);
                *(ushort4*)(sB + n * LDK + k4) = h;
            }
        }
        __syncthreads();
        #pragma unroll
        for (int kk = 0; kk < BK; kk += 32) {
            bf16x8 af[4], bfr[4];
            #pragma unroll
            for (int i = 0; i < 4; ++i) {
                af[i]  = *(const bf16x8*)(sA + (wm * 64 + i * 16 + l15) * LDK + kk + quad * 8);
                bfr[i] = *(const bf16x8*)(sB + (wn * 64 + i * 16 + l15) * LDK + kk + quad * 8);
            }
            #pragma unroll
            for (int i = 0; i < 4; ++i)
                #pragma unroll
                for (int j = 0; j < 4; ++j)
                    acc[i][j] = __builtin_amdgcn_mfma_f32_16x16x32_bf16(af[i], bfr[j], acc[i][j], 0, 0, 0);
        }
    }

    bool val[4];
    #pragma unroll
    for (int j = 0; j < 4; ++j) val[j] = (n0 + wn * 64 + j * 16 + l15) < VV;

    if constexpr (STATS) {
        __shared__ float sM[2][BM], sS[2][BM];
        #pragma unroll
        for (int i = 0; i < 4; ++i) {
            #pragma unroll
            for (int r = 0; r < 4; ++r) {
                float m1 = -INFINITY;
                #pragma unroll
                for (int j = 0; j < 4; ++j) if (val[j]) m1 = fmaxf(m1, acc[i][j][r]);
                #pragma unroll
                for (int off = 8; off >= 1; off >>= 1) m1 = fmaxf(m1, __shfl_xor(m1, off, 64));
                float s = 0.f;
                #pragma unroll
                for (int j = 0; j < 4; ++j) if (val[j]) s += __expf(acc[i][j][r] - m1);
                #pragma unroll
                for (int off = 8; off >= 1; off >>= 1) s += __shfl_xor(s, off, 64);
                if (l15 == 0) {
                    const int mloc = wm * 64 + i * 16 + quad * 4 + r;
                    sM[wn][mloc] = m1;
                    sS[wn][mloc] = s;
                }
            }
        }
        __syncthreads();
        if (t < BM) {
            const float Ma = sM[0][t], Mb = sM[1][t];
            const float nM = fmaxf(Ma, Mb);
            const float S  = sS[0][t] * __expf(Ma - nM) + sS[1][t] * __expf(Mb - nM);
            const size_t o = (size_t)(m0 + t) * NCHUNK + cn;
            pmax[o] = nM;
            psum[o] = S;
        }
    } else {
        __shared__ float sMr[BM], sIr[BM], sTr[BM];
        if (t < BM) {
            sMr[t] = rowM[m0 + t];
            sIr[t] = rowInvS[m0 + t];
            sTr[t] = rowTh[m0 + t];
        }
        float* stage = (float*)smem_raw;      // 32 rows x 132 f32 = 16,896 B <= 36,864 B
        #pragma unroll
        for (int h = 0; h < 4; ++h) {
            __syncthreads();                  // h=0: also guards sA/sB reuse + sMr visibility
            if (wm == (h >> 1)) {
                const int ibase = (h & 1) * 2;
                #pragma unroll
                for (int ii = 0; ii < 2; ++ii) {
                    const int i = ibase + ii;
                    #pragma unroll
                    for (int r = 0; r < 4; ++r) {
                        const int ml = wm * 64 + i * 16 + quad * 4 + r;
                        const int rl = ii * 16 + quad * 4 + r;            // [0,32)
                        const float M = sMr[ml], inv = sIr[ml], th = sTr[ml];
                        #pragma unroll
                        for (int j = 0; j < 4; ++j) {
                            const float y = __expf(acc[i][j][r] - M) * inv;
                            stage[rl * 132 + wn * 64 + j * 16 + l15] = y;
                            if (val[j] && y >= th) {
                                const int gm = m0 + ml;
                                const int gn = n0 + wn * 64 + j * 16 + l15;
                                const int p = atomicAdd(&cand_cnt[gm], 1);
                                if (p < MAXCAND) cand_idx[gm * MAXCAND + p] = gn;
                            }
                        }
                    }
                }
            }
            __syncthreads();
            // coalesced stream-out: 32 rows x 128 cols; wave covers 2 full 512B row-segments
            #pragma unroll
            for (int k = 0; k < 4; ++k) {
                const int f = t + k * 256;
                const int row = f >> 5, c4 = f & 31;
                const int gcol = n0 + c4 * 4;
                if (gcol + 3 < VV) {          // VV - 390*BN = 80 ≡ 0 mod 4: no partial float4
                    const f32x4 v = *(const f32x4*)&stage[row * 132 + c4 * 4];
                    __builtin_nontemporal_store(v,
                        (f32x4*)(out + (size_t)(m0 + h * 32 + row) * VV + gcol));
                }
            }
        }
    }
}

// ---------------- Kernel 3: merge per-chunk stats -> rowM, invS, threshold ----------------
__global__ __launch_bounds__(64) void k_rowstats(
    const float* __restrict__ pmax, const float* __restrict__ psum,
    float* __restrict__ rowM, float* __restrict__ rowInvS, float* __restrict__ rowTh,
    int* __restrict__ cand_cnt)
{
    const int b = blockIdx.x, t = threadIdx.x;
    float M = -INFINITY, S = 0.f;
    float top[TOPK];
    #pragma unroll
    for (int j = 0; j < TOPK; ++j) top[j] = -INFINITY;

    for (int c = t; c < NCHUNK; c += 64) {
        const float m = pmax[(size_t)b * NCHUNK + c];
        const float s = psum[(size_t)b * NCHUNK + c];
        const float nM = fmaxf(M, m);
        S = S * __expf(M - nM) + s * __expf(m - nM);
        M = nM;
        if (m > top[TOPK - 1]) {
            float v = m;
            #pragma unroll
            for (int p = 0; p < TOPK; ++p) {
                const float hi = fmaxf(top[p], v), lo = fminf(top[p], v);
                top[p] = hi; v = lo;
            }
        }
    }
    #pragma unroll
    for (int off = 32; off; off >>= 1) {
        const float m2 = __shfl_xor(M, off, 64);
        const float s2 = __shfl_xor(S, off, 64);
        const float nM = fmaxf(M, m2);
        S = S * __expf(M - nM) + s2 * __expf(m2 - nM);
        M = nM;
    }
    float v10 = -INFINITY;
    for (int k = 0; k < TOPK; ++k) {
        float g = top[0];
        #pragma unroll
        for (int off = 32; off; off >>= 1) g = fmaxf(g, __shfl_xor(g, off, 64));
        v10 = g;
        const unsigned long long mk = __ballot(top[0] == g);
        if (mk && t == __ffsll(mk) - 1) {
            #pragma unroll
            for (int p = 0; p < TOPK - 1; ++p) top[p] = top[p + 1];
            top[TOPK - 1] = -INFINITY;
        }
    }
    if (t == 0) {
        rowM[b] = M;
        const float inv = 1.f / S;
        rowInvS[b] = inv;
        rowTh[b] = 0.90f * __expf(v10 - M) * inv;
        cand_cnt[b] = 0;
    }
}

// ---------------- Kernel 5: exact fp32 rescore of candidates -> final indices ----------------
__global__ __launch_bounds__(64) void k_rescore(
    const float* __restrict__ phrase, const float* __restrict__ CE,
    const int* __restrict__ cand_idx, const int* __restrict__ cand_cnt,
    float* __restrict__ topk_out)
{
    const int b = blockIdx.x, lane = threadIdx.x;
    int cnt = cand_cnt[b];
    if (cnt > MAXCAND) cnt = MAXCAND;
    __shared__ float s_val[MAXCAND];
    __shared__ int   s_idx[MAXCAND];

    if (lane < MAXCAND) { s_val[lane] = -INFINITY; s_idx[lane] = 0x7ffffff0; }
    __syncthreads();

    const float4 ph = *(const float4*)(phrase + (size_t)b * DD + lane * 4);
    for (int c = 0; c < cnt; ++c) {
        const int id = cand_idx[b * MAXCAND + c];
        const float4 ce = *(const float4*)(CE + (size_t)id * DD + lane * 4);
        float d = ph.x * ce.x + ph.y * ce.y + ph.z * ce.z + ph.w * ce.w;
        #pragma unroll
        for (int off = 32; off; off >>= 1) d += __shfl_xor(d, off, 64);
        if (lane == 0) { s_val[c] = d; s_idx[c] = id; }
    }
    __syncthreads();
    if (lane == 0) {
        for (int j = 0; j < TOPK; ++j) {
            int best = j;
            for (int c = j + 1; c < cnt; ++c) {
                if (s_val[c] > s_val[best] ||
                    (s_val[c] == s_val[best] && s_idx[c] < s_idx[best])) best = c;
            }
            const float bv = s_val[best]; const int bi = s_idx[best];
            s_val[best] = s_val[j]; s_idx[best] = s_idx[j];
            s_val[j] = bv; s_idx[j] = bi;
            topk_out[b * TOPK + j] = (float)bi;
        }
    }
}

extern "C" void kernel_launch(void* const* d_in, const int* in_sizes, int n_in,
                              void* d_out, int out_size, void* d_ws, size_t ws_size,
                              hipStream_t stream) {
    const int*   wl_ids = (const int*)d_in[0];
    const int*   wr_ids = (const int*)d_in[1];
    const int*   cl_ids = (const int*)d_in[2];
    const int*   cr_ids = (const int*)d_in[3];
    const float* WE     = (const float*)d_in[4];
    const float* CE     = (const float*)d_in[5];
    const float* W_a    = (const float*)d_in[6];
    const float* b_a    = (const float*)d_in[7];
    const float* W_c    = (const float*)d_in[8];
    const float* b_c    = (const float*)d_in[9];

    float* out = (float*)d_out;
    float* ws  = (float*)d_ws;

    // Base layout: 5,038,080 B — within the 5,050,368 B footprint proven by prior sessions.
    float* phrase  = ws;                                        // 262144 f
    unsigned short* phraseb = (unsigned short*)(ws + 262144);   // 131072 f
    float* pmax    = ws + 262144 + 131072;                      // 400384 f
    float* psum    = pmax + (size_t)BB * NCHUNK;                // 400384 f
    float* rowM    = psum + (size_t)BB * NCHUNK;                // 1024 f
    float* rowInvS = rowM + BB;                                 // 1024 f
    float* rowTh   = rowInvS + BB;                              // 1024 f
    int*   cand_idx = (int*)(rowTh + BB);                       // BB*60 i
    int*   cand_cnt = cand_idx + (size_t)BB * MAXCAND;          // 1024 i
    float* topk_out = out + (size_t)BB * VV;

    const size_t baseBytes = (size_t)((char*)(cand_cnt + BB) - (char*)ws);

    // ext1 (new phrase pipeline): alignbuf 2 MB + wordsum 1 MB + aggsum 1 MB
    float* alignbuf = (float*)((char*)ws + baseBytes);          // 2048*256 f
    float* wordsum  = alignbuf + (size_t)2 * BB * DD;           // 1024*256 f
    float* aggsum   = wordsum + (size_t)BB * DD;                // 1024*256 f
    const size_t ext1End = baseBytes + (size_t)4 * BB * DD * 4; // +4,194,304 B
    const bool newphrase = ws_size >= ext1End;

    const size_t ceOff = ((newphrase ? ext1End : baseBytes) + 255) & ~(size_t)255;
    const bool bf16ce = ws_size >= ceOff + (size_t)VV * DD * 2;  // +25.6 MB, runtime-gated
    unsigned short* CEb = (unsigned short*)((char*)ws + ceOff);

    if (newphrase) {
        k_align<<<256, 256, 0, stream>>>(wl_ids, wr_ids, WE, W_a, b_a, alignbuf, wordsum);
        k_attn<<<BB, 256, 0, stream>>>(cl_ids, cr_ids, CE, alignbuf, aggsum);
        k_phrase2<<<256, 256, 0, stream>>>(wordsum, aggsum, W_c, b_c, phrase, phraseb);
    } else {
        k_phrase<<<BB, 256, 0, stream>>>(wl_ids, wr_ids, cl_ids, cr_ids,
                                         WE, CE, W_a, b_a, W_c, b_c, phrase, phraseb);
    }
    if (bf16ce) {
        k_prep<<<(VV * DD / 8 + 255) / 256, 256, 0, stream>>>(CE, CEb);
        k_gemm<true, true><<<NWG, 256, 0, stream>>>(phraseb, CE, CEb, out,
            pmax, psum, rowM, rowInvS, rowTh, cand_idx, cand_cnt);
        k_rowstats<<<BB, 64, 0, stream>>>(pmax, psum, rowM, rowInvS, rowTh, cand_cnt);
        k_gemm<false, true><<<NWG, 256, 0, stream>>>(phraseb, CE, CEb, out,
            pmax, psum, rowM, rowInvS, rowTh, cand_idx, cand_cnt);
    } else {
        k_gemm<true, false><<<NWG, 256, 0, stream>>>(phraseb, CE, CEb, out,
            pmax, psum, rowM, rowInvS, rowTh, cand_idx, cand_cnt);
        k_rowstats<<<BB, 64, 0, stream>>>(pmax, psum, rowM, rowInvS, rowTh, cand_cnt);
        k_gemm<false, false><<<NWG, 256, 0, stream>>>(phraseb, CE, CEb, out,
            pmax, psum, rowM, rowInvS, rowTh, cand_idx, cand_cnt);
    }
    k_rescore<<<BB, 64, 0, stream>>>(phrase, CE, cand_idx, cand_cnt, topk_out);
}